// Round 1
// baseline (811.094 us; speedup 1.0000x reference)
//
#include <hip/hip_runtime.h>

#define KS 41
#define PAD 20
#define H 512
#define W 512
#define CH 6

// Fused strip geometry
#define WS   128               // output strip width
#define HS   256               // output strip height
#define RB   32                // output rows produced per iteration
#define NIT  (HS / RB)         // 8 iterations
#define RING 72                // ring rows = RB + 2*PAD
#define RSTR 132               // ring row stride (floats); 132*4B shifts banks per row

__device__ __forceinline__ int reflect511(int i) {
    // valid for i in (-512, 1022); H == W == 512
    return (H - 1) - abs((H - 1) - abs(i));
}

// Coefficients -> SGPRs, no LDS, no barrier: lane j (j<41) computes row-sum j
// of the separable 2D kernel (== normalized 1D gaussian), readlane broadcasts.
__device__ __forceinline__ void load_coeffs(const float* __restrict__ w, int c,
                                            int lane, float gk[KS]) {
    float my = 0.f;
    if (lane < KS) {
        const float* wr = w + (size_t)c * KS * KS + (size_t)lane * KS;
        #pragma unroll
        for (int j = 0; j < KS; ++j) my += wr[j];
    }
    #pragma unroll
    for (int j = 0; j < KS; ++j)
        gk[j] = __uint_as_float(__builtin_amdgcn_readlane(__float_as_uint(my), j));
}

// One horizontal-blur task: ring row `id` (absolute raw row Y0-20+id, row-reflected),
// segment s (8 output cols). Windows read straight from global: all float4 loads are
// 16B-aligned because x0 + 8s - 20 is a multiple of 4. Result -> LDS ring.
__device__ __forceinline__ void htask(const float* __restrict__ img,
                                      float* __restrict__ ring,
                                      const float gk[KS],
                                      int id, int s, int Y0, int x0) {
    const int ry = reflect511(Y0 - PAD + id);
    const float* row = img + (size_t)ry * W;
    const int xs = x0 + 8 * s - PAD;

    float win[48];
    if (xs >= 0 && xs <= W - 48) {
        const float4* p = (const float4*)(row + xs);
        #pragma unroll
        for (int m = 0; m < 12; ++m) {
            float4 v = p[m];
            win[4 * m + 0] = v.x; win[4 * m + 1] = v.y;
            win[4 * m + 2] = v.z; win[4 * m + 3] = v.w;
        }
    } else {
        // only boundary strips (bx==0, s<=2) / (bx==3, s>=13) take this path
        #pragma unroll
        for (int j = 0; j < 48; ++j) win[j] = row[reflect511(xs + j)];
    }

    float acc[8];
    #pragma unroll
    for (int i = 0; i < 8; ++i) acc[i] = 0.f;
    #pragma unroll
    for (int j = 0; j < KS; ++j) {
        const float g = gk[j];
        #pragma unroll
        for (int i = 0; i < 8; ++i) acc[i] += g * win[j + i];
    }

    const int slot = id % RING;
    float* d = ring + slot * RSTR + 8 * s;
    *(float4*)(d)     = make_float4(acc[0], acc[1], acc[2], acc[3]);
    *(float4*)(d + 4) = make_float4(acc[4], acc[5], acc[6], acc[7]);
}

// Fused separable blur: one block = 128x256 output strip.
// LDS ring of 72 hblur rows; per iteration: h-blur 32 new rows (2 tasks/thread),
// then vertical conv register-blocked 4 rows x 4 cols per thread (float4 LDS
// reads, contiguous -> conflict-free; float4 global stores).
__global__ __launch_bounds__(256, 4)
void gauss_fused_kernel(const float* __restrict__ x, const float* __restrict__ w,
                        float* __restrict__ out) {
    __shared__ float ring[RING * RSTR];   // 38016 B -> 4 blocks/CU

    const int tid = threadIdx.x;
    const int bx  = blockIdx.x;           // 0..3  column strip
    const int by  = blockIdx.y;           // 0..1  row strip
    const int img = blockIdx.z;           // 0..95
    const int c   = img % CH;
    const int x0  = bx * WS;
    const int Y0  = by * HS;

    float gk[KS];
    load_coeffs(w, c, tid & 63, gk);

    const float* imgp = x + (size_t)img * H * W;

    // prologue: fill ring ids 0..39 (hblur rows Y0-20 .. Y0+19)
    for (int t = tid; t < 2 * PAD * 16; t += 256)
        htask(imgp, ring, gk, t >> 4, t & 15, Y0, x0);

    const int cg = tid & 31;              // column group: cols x0 + 4*cg .. +3
    const int rg = tid >> 5;              // row group 0..7: rows +4*rg .. +3
    float* obase = out + ((size_t)img * H + (size_t)(Y0 + 4 * rg)) * W + x0 + 4 * cg;

    for (int k = 0; k < NIT; ++k) {
        // h-blur ring ids 40+32k .. 71+32k (2 tasks per thread, no guards)
        {
            const int base = 2 * PAD + RB * k;
            htask(imgp, ring, gk, base + (tid >> 4), tid & 15, Y0, x0);
            const int t2 = tid + 256;
            htask(imgp, ring, gk, base + (t2 >> 4), t2 & 15, Y0, x0);
        }
        __syncthreads();

        // vertical conv: 16 outputs/thread (4 rows x 4 cols)
        {
            float acc[4][4];
            #pragma unroll
            for (int i = 0; i < 4; ++i)
                #pragma unroll
                for (int jj = 0; jj < 4; ++jj) acc[i][jj] = 0.f;

            const int s0 = (RB * k + 4 * rg) % RING;   // first window ring slot
            int fo = s0 * RSTR + 4 * cg;               // float offset, incremental
            #pragma unroll
            for (int j = 0; j < 44; ++j) {
                const float4 v = *(const float4*)(ring + fo);
                fo += RSTR;
                if (fo >= RING * RSTR) fo -= RING * RSTR;
                #pragma unroll
                for (int rr = 0; rr < 4; ++rr) {
                    const int tap = j - rr;            // compile-time per (j,rr)
                    if (tap >= 0 && tap < KS) {
                        const float g = gk[tap];
                        acc[rr][0] += g * v.x;
                        acc[rr][1] += g * v.y;
                        acc[rr][2] += g * v.z;
                        acc[rr][3] += g * v.w;
                    }
                }
            }

            float* o = obase + (size_t)(RB * k) * W;
            #pragma unroll
            for (int rr = 0; rr < 4; ++rr)
                *(float4*)(o + (size_t)rr * W) =
                    make_float4(acc[rr][0], acc[rr][1], acc[rr][2], acc[rr][3]);
        }
        __syncthreads();   // ring slots of dead rows get overwritten next iter
    }
}

extern "C" void kernel_launch(void* const* d_in, const int* in_sizes, int n_in,
                              void* d_out, int out_size, void* d_ws, size_t ws_size,
                              hipStream_t stream) {
    const float* x = (const float*)d_in[0];   // [16,6,512,512]
    const float* w = (const float*)d_in[1];   // [6,1,41,41]
    float* out = (float*)d_out;
    (void)in_sizes; (void)n_in; (void)out_size; (void)d_ws; (void)ws_size;

    gauss_fused_kernel<<<dim3(W / WS, H / HS, 16 * CH), 256, 0, stream>>>(x, w, out);
}

// Round 2
// 532.947 us; speedup vs baseline: 1.5219x; 1.5219x over previous
//
#include <hip/hip_runtime.h>

#define KS 41
#define PAD 20
#define H 512
#define W 512
#define CH 6

// Fused strip geometry
#define WS   128               // output strip width
#define HS   256               // output strip height
#define RB   32                // output rows produced per iteration
#define NIT  (HS / RB)         // 8 iterations
#define RING 72                // ring rows = RB + 2*PAD
#define RSTR 132               // ring row stride (floats); bank-shifts rows by 4

__device__ __forceinline__ int reflect511(int i) {
    // valid for i in (-512, 1022); H == W == 512
    return (H - 1) - abs((H - 1) - abs(i));
}

// Coefficients -> SGPRs, no LDS, no barrier: lane j (j<41) computes row-sum j
// of the separable 2D kernel (== normalized 1D gaussian), readlane broadcasts.
__device__ __forceinline__ void load_coeffs(const float* __restrict__ w, int c,
                                            int lane, float gk[KS]) {
    float my = 0.f;
    if (lane < KS) {
        const float* wr = w + (size_t)c * KS * KS + (size_t)lane * KS;
        #pragma unroll
        for (int j = 0; j < KS; ++j) my += wr[j];
    }
    #pragma unroll
    for (int j = 0; j < KS; ++j)
        gk[j] = __uint_as_float(__builtin_amdgcn_readlane(__float_as_uint(my), j));
}

// One horizontal-blur task, STREAMING form (no win[] array -> no scratch):
// for each loaded float at window position pos, scatter into the <=8 output
// accumulators with compile-time tap indices. 328 FMAs, ~16 live VGPRs.
__device__ __forceinline__ void htask(const float* __restrict__ img,
                                      float* __restrict__ ring,
                                      const float gk[KS],
                                      int id, int s, int Y0, int x0) {
    const int ry = reflect511(Y0 - PAD + id);
    const float* row = img + (size_t)ry * W;
    const int xs = x0 + 8 * s - PAD;     // multiple of 4 -> aligned float4 loads

    float acc[8];
    #pragma unroll
    for (int i = 0; i < 8; ++i) acc[i] = 0.f;

    if (xs >= 0 && xs <= W - 48) {
        const float4* p = (const float4*)(row + xs);
        #pragma unroll
        for (int m = 0; m < 12; ++m) {
            const float4 q = p[m];
            const float f[4] = {q.x, q.y, q.z, q.w};
            #pragma unroll
            for (int t = 0; t < 4; ++t) {
                const int pos = 4 * m + t;
                #pragma unroll
                for (int i = 0; i < 8; ++i) {
                    const int tap = pos - i;            // compile-time
                    if (tap >= 0 && tap < KS)
                        acc[i] += gk[tap] * f[t];
                }
            }
        }
    } else {
        // boundary strips only (bx==0 s<=2, bx==3 s>=13)
        #pragma unroll
        for (int pos = 0; pos < 48; ++pos) {
            const float f = row[reflect511(xs + pos)];
            #pragma unroll
            for (int i = 0; i < 8; ++i) {
                const int tap = pos - i;
                if (tap >= 0 && tap < KS)
                    acc[i] += gk[tap] * f;
            }
        }
    }

    const int slot = id % RING;
    float* d = ring + slot * RSTR + 8 * s;
    *(float4*)(d)     = make_float4(acc[0], acc[1], acc[2], acc[3]);
    *(float4*)(d + 4) = make_float4(acc[4], acc[5], acc[6], acc[7]);
}

// Fused separable blur: one block = 128x256 output strip, grid = 768 = 3/CU.
// LDS ring of 72 hblur rows; per iteration: h-blur 32 new rows (2 tasks/thread),
// then vertical conv register-blocked 4 rows x 4 cols per thread (float4 LDS
// reads, contiguous -> conflict-free; float4 global stores).
__global__ __launch_bounds__(256, 3)
void gauss_fused_kernel(const float* __restrict__ x, const float* __restrict__ w,
                        float* __restrict__ out) {
    __shared__ float ring[RING * RSTR];   // 38016 B

    const int tid = threadIdx.x;
    const int bx  = blockIdx.x;           // 0..3  column strip
    const int by  = blockIdx.y;           // 0..1  row strip
    const int img = blockIdx.z;           // 0..95
    const int c   = img % CH;
    const int x0  = bx * WS;
    const int Y0  = by * HS;

    float gk[KS];
    load_coeffs(w, c, tid & 63, gk);

    const float* imgp = x + (size_t)img * H * W;

    // prologue: fill ring ids 0..39 (hblur rows Y0-20 .. Y0+19)
    for (int t = tid; t < 2 * PAD * 16; t += 256)
        htask(imgp, ring, gk, t >> 4, t & 15, Y0, x0);

    const int cg = tid & 31;              // column group: cols x0 + 4*cg .. +3
    const int rg = tid >> 5;              // row group 0..7: rows +4*rg .. +3
    float* obase = out + ((size_t)img * H + (size_t)(Y0 + 4 * rg)) * W + x0 + 4 * cg;

    for (int k = 0; k < NIT; ++k) {
        // h-blur ring ids 40+32k .. 71+32k (2 tasks per thread, no guards)
        {
            const int base = 2 * PAD + RB * k;
            htask(imgp, ring, gk, base + (tid >> 4), tid & 15, Y0, x0);
            const int t2 = tid + 256;
            htask(imgp, ring, gk, base + (t2 >> 4), t2 & 15, Y0, x0);
        }
        __syncthreads();

        // vertical conv: 16 outputs/thread (4 rows x 4 cols)
        {
            float acc[4][4];
            #pragma unroll
            for (int i = 0; i < 4; ++i)
                #pragma unroll
                for (int jj = 0; jj < 4; ++jj) acc[i][jj] = 0.f;

            const int s0 = (RB * k + 4 * rg) % RING;   // first window ring slot
            int fo = s0 * RSTR + 4 * cg;               // float offset, incremental
            #pragma unroll
            for (int j = 0; j < 44; ++j) {
                const float4 v = *(const float4*)(ring + fo);
                fo += RSTR;
                if (fo >= RING * RSTR) fo -= RING * RSTR;
                #pragma unroll
                for (int rr = 0; rr < 4; ++rr) {
                    const int tap = j - rr;            // compile-time per (j,rr)
                    if (tap >= 0 && tap < KS) {
                        const float g = gk[tap];
                        acc[rr][0] += g * v.x;
                        acc[rr][1] += g * v.y;
                        acc[rr][2] += g * v.z;
                        acc[rr][3] += g * v.w;
                    }
                }
            }

            float* o = obase + (size_t)(RB * k) * W;
            #pragma unroll
            for (int rr = 0; rr < 4; ++rr)
                *(float4*)(o + (size_t)rr * W) =
                    make_float4(acc[rr][0], acc[rr][1], acc[rr][2], acc[rr][3]);
        }
        __syncthreads();   // ring slots of dead rows get overwritten next iter
    }
}

extern "C" void kernel_launch(void* const* d_in, const int* in_sizes, int n_in,
                              void* d_out, int out_size, void* d_ws, size_t ws_size,
                              hipStream_t stream) {
    const float* x = (const float*)d_in[0];   // [16,6,512,512]
    const float* w = (const float*)d_in[1];   // [6,1,41,41]
    float* out = (float*)d_out;
    (void)in_sizes; (void)n_in; (void)out_size; (void)d_ws; (void)ws_size;

    gauss_fused_kernel<<<dim3(W / WS, H / HS, 16 * CH), 256, 0, stream>>>(x, w, out);
}

// Round 3
// 451.596 us; speedup vs baseline: 1.7961x; 1.1801x over previous
//
#include <hip/hip_runtime.h>

#define KS 41
#define PAD 20
#define H 512
#define W 512
#define CH 6

__device__ __forceinline__ int reflect511(int i) {
    // valid for i in (-512, 1022); H == W == 512
    return (H - 1) - abs((H - 1) - abs(i));
}

__device__ __forceinline__ int reflect_idx(int i, int n) {
    if (i < 0) i = -i;
    if (i >= n) i = 2 * n - 2 - i;
    return i;
}

__device__ __forceinline__ float uniform_f(float v) {
    return __uint_as_float(__builtin_amdgcn_readfirstlane(__float_as_uint(v)));
}

// Coefficients -> SGPRs, no LDS, no barrier: lane j (j<41) computes row-sum j
// of the separable 2D kernel (== normalized 1D gaussian), readlane broadcasts.
__device__ __forceinline__ void load_coeffs(const float* __restrict__ w, int c,
                                            int lane, float gk[KS]) {
    float my = 0.f;
    if (lane < KS) {
        const float* wr = w + (size_t)c * KS * KS + (size_t)lane * KS;
        #pragma unroll
        for (int j = 0; j < KS; ++j) my += wr[j];
    }
    #pragma unroll
    for (int j = 0; j < KS; ++j)
        gk[j] = __uint_as_float(__builtin_amdgcn_readlane(__float_as_uint(my), j));
}

// ---------------- Pass 1: horizontal blur, x -> ws ----------------
// LDS-free streaming. 4 outputs/lane: window = 44 floats = 11 aligned float4
// loads with 16B lane stride -> every load instruction is 1KB contiguous
// (the 11x overlap between successive instructions is pure L1 hits).
// 4 rows per wave amortize the coeff preamble. ~10 live VGPRs in the loop.
#define HROWS 16   // rows per block (4 waves x 4 rows)

__global__ __launch_bounds__(256, 4)
void gauss_h_kernel(const float* __restrict__ x, const float* __restrict__ w,
                    float* __restrict__ ws) {
    const int tid = threadIdx.x;
    const int l   = tid & 63;
    const int wv  = tid >> 6;
    const int img = blockIdx.y;              // 0..95
    const int c   = img % CH;
    const int R0  = blockIdx.x * HROWS + wv * 4;

    float gk[KS];
    load_coeffs(w, c, l, gk);

    const float* imgp = x + (size_t)img * H * W;
    float* wsp = ws + (size_t)img * H * W;

    for (int rr = 0; rr < 4; ++rr) {
        const int row = R0 + rr;
        const float* rp = imgp + (size_t)row * W;
        float* op = wsp + (size_t)row * W;

        #pragma unroll
        for (int hh = 0; hh < 2; ++hh) {
            const int x0 = 256 * hh + 4 * l;     // output col base
            const int xs = x0 - PAD;             // window start, multiple of 4
            float a0 = 0.f, a1 = 0.f, a2 = 0.f, a3 = 0.f;

            if (xs >= 0 && xs <= W - 44) {
                const float4* p = (const float4*)(rp + xs);
                #pragma unroll
                for (int m = 0; m < 11; ++m) {
                    const float4 q = p[m];
                    const float f[4] = {q.x, q.y, q.z, q.w};
                    #pragma unroll
                    for (int t = 0; t < 4; ++t) {
                        const int k = 4 * m + t;          // window pos 0..43
                        if (k <= 40)            a0 += gk[k]     * f[t];
                        if (k >= 1 && k <= 41)  a1 += gk[k - 1] * f[t];
                        if (k >= 2 && k <= 42)  a2 += gk[k - 2] * f[t];
                        if (k >= 3)             a3 += gk[k - 3] * f[t];
                    }
                }
            } else {
                // boundary lanes only (hh==0: l<5 ; hh==1: l>=58)
                #pragma unroll
                for (int k = 0; k < 44; ++k) {
                    const float f = rp[reflect511(xs + k)];
                    if (k <= 40)            a0 += gk[k]     * f;
                    if (k >= 1 && k <= 41)  a1 += gk[k - 1] * f;
                    if (k >= 2 && k <= 42)  a2 += gk[k - 2] * f;
                    if (k >= 3)             a3 += gk[k - 3] * f;
                }
            }
            *(float4*)(op + x0) = make_float4(a0, a1, a2, a3);
        }
    }
}

// ---------------- Pass 2: vertical blur, ws -> out ----------------
// LDS-free streaming. Thread = 16 output rows x 4 cols. 56 row-float4 loads,
// each instruction 1KB contiguous across the wave; ws rows are L2/L3-resident.
// acc[16] float4 with compile-time indices -> pure registers.
#define VROWS 16

__global__ __launch_bounds__(256, 2)
void gauss_v_kernel(const float* __restrict__ ws, const float* __restrict__ w,
                    float* __restrict__ out) {
    const int tid = threadIdx.x;
    const int img = blockIdx.y;                  // 0..95
    const int c   = img % CH;
    const int t   = blockIdx.x * 256 + tid;      // 0..4095
    const int cq  = t & 127;                     // float4 col group 0..127
    const int rg  = t >> 7;                      // row group 0..31
    const int y0  = rg * VROWS;

    float gk[KS];
    load_coeffs(w, c, tid & 63, gk);

    const float* wsp = ws + (size_t)img * H * W + 4 * cq;
    float* op = out + (size_t)img * H * W + 4 * cq;

    float4 acc[VROWS];
    #pragma unroll
    for (int i = 0; i < VROWS; ++i) acc[i] = make_float4(0.f, 0.f, 0.f, 0.f);

    #pragma unroll
    for (int i = 0; i < VROWS + 2 * PAD; ++i) {   // 56 input rows
        const int r = reflect511(y0 - PAD + i);
        const float4 v = *(const float4*)(wsp + (size_t)r * W);
        #pragma unroll
        for (int oi = 0; oi < VROWS; ++oi) {
            const int j = i - oi;                 // compile-time tap per (i,oi)
            if (j >= 0 && j < KS) {
                const float g = gk[j];
                acc[oi].x += g * v.x; acc[oi].y += g * v.y;
                acc[oi].z += g * v.z; acc[oi].w += g * v.w;
            }
        }
    }

    #pragma unroll
    for (int oi = 0; oi < VROWS; ++oi)
        *(float4*)(op + (size_t)(y0 + oi) * W) = acc[oi];
}

// ---------------- Fallback: known-correct fused kernel ----------------
#define TW 64
#define TH 128
#define TMPH (TH + 2 * PAD)  // 168

__global__ __launch_bounds__(256, 3)
void gauss_blur_fused_kernel(const float* __restrict__ x,
                             const float* __restrict__ w,
                             float* __restrict__ out) {
    __shared__ float g_s[KS];
    __shared__ float tmp[TMPH * TW];

    const int tid = threadIdx.x;
    const int bx = blockIdx.x, by = blockIdx.y, bz = blockIdx.z;
    const int c = bz % CH;

    if (tid < KS) {
        const float* wr = w + (size_t)c * KS * KS + (size_t)tid * KS;
        float s = 0.f;
        #pragma unroll
        for (int j = 0; j < KS; ++j) s += wr[j];
        g_s[tid] = s;
    }
    __syncthreads();

    float gr[KS];
    #pragma unroll
    for (int j = 0; j < KS; ++j) gr[j] = uniform_f(g_s[j]);

    const size_t img_off = (size_t)bz * (H * W);
    const float* img = x + img_off;
    const int x_tile = bx * TW;

    for (int gid = tid; gid < TMPH * (TW / 8); gid += 256) {
        const int r  = gid >> 3;
        const int gx = gid & 7;
        const int gy = reflect_idx(by * TH - PAD + r, H);
        const int x0 = x_tile + gx * 8;
        const float* row = img + (size_t)gy * W;

        float s[8];
        #pragma unroll
        for (int k = 0; k < 8; ++k) s[k] = 0.f;

        if (x0 >= PAD && x0 + 27 <= W - 1) {
            const float4* p = (const float4*)(row + x0 - PAD);
            #pragma unroll
            for (int m = 0; m < 12; ++m) {
                const float4 v = p[m];
                const float f[4] = {v.x, v.y, v.z, v.w};
                #pragma unroll
                for (int t = 0; t < 4; ++t) {
                    const int pos = 4 * m + t;
                    #pragma unroll
                    for (int k = 0; k < 8; ++k) {
                        const int tap = pos - k;
                        if (tap >= 0 && tap < KS) s[k] += gr[tap] * f[t];
                    }
                }
            }
        } else {
            #pragma unroll
            for (int pos = 0; pos < 48; ++pos) {
                const float f = row[reflect_idx(x0 - PAD + pos, W)];
                #pragma unroll
                for (int k = 0; k < 8; ++k) {
                    const int tap = pos - k;
                    if (tap >= 0 && tap < KS) s[k] += gr[tap] * f;
                }
            }
        }
        float* dstp = &tmp[r * TW + gx * 8];
        #pragma unroll
        for (int k = 0; k < 8; ++k) dstp[k] = s[k];
    }
    __syncthreads();

    const int lx = tid & 63;
    const int yg = tid >> 6;
    float* o = out + img_off;

    #pragma unroll
    for (int cc = 0; cc < 2; ++cc) {
        const int yc = yg * 32 + cc * 16;
        float col[56];
        #pragma unroll
        for (int i = 0; i < 56; ++i)
            col[i] = tmp[(yc + i) * TW + lx];
        #pragma unroll
        for (int y = 0; y < 16; ++y) {
            float s = 0.f;
            #pragma unroll
            for (int j = 0; j < KS; ++j) s += gr[j] * col[y + j];
            o[(size_t)(by * TH + yc + y) * W + x_tile + lx] = s;
        }
    }
}

extern "C" void kernel_launch(void* const* d_in, const int* in_sizes, int n_in,
                              void* d_out, int out_size, void* d_ws, size_t ws_size,
                              hipStream_t stream) {
    const float* x = (const float*)d_in[0];   // [16,6,512,512]
    const float* w = (const float*)d_in[1];   // [6,1,41,41]
    float* out = (float*)d_out;
    (void)in_sizes; (void)n_in; (void)out_size;

    const size_t need = (size_t)16 * CH * H * W * sizeof(float);
    if (ws_size >= need) {
        float* ws = (float*)d_ws;
        gauss_h_kernel<<<dim3(H / HROWS, 16 * CH), 256, 0, stream>>>(x, w, ws);
        gauss_v_kernel<<<dim3(16, 16 * CH), 256, 0, stream>>>(ws, w, out);
    } else {
        dim3 grid(W / TW, H / TH, 16 * CH);
        gauss_blur_fused_kernel<<<grid, 256, 0, stream>>>(x, w, out);
    }
}

// Round 4
// 252.996 us; speedup vs baseline: 3.2060x; 1.7850x over previous
//
#include <hip/hip_runtime.h>

#define KS 41
#define PAD 20
#define H 512
#define W 512
#define CH 6
#define PROW 552   // padded row: 20 + 512 + 20

__device__ __forceinline__ int reflect_idx(int i, int n) {
    if (i < 0) i = -i;
    if (i >= n) i = 2 * n - 2 - i;
    return i;
}

__device__ __forceinline__ int reflect511(int i) {
    // valid for i in (-512, 1022); H == W == 512
    return (H - 1) - abs((H - 1) - abs(i));
}

__device__ __forceinline__ float uniform_f(float v) {
    return __uint_as_float(__builtin_amdgcn_readfirstlane(__float_as_uint(v)));
}

// Coefficients -> SGPRs, no LDS, no barrier: lane j (j<41) computes row-sum j
// of the separable 2D kernel (== normalized 1D gaussian), readlane broadcasts.
__device__ __forceinline__ void load_coeffs(const float* __restrict__ w, int c,
                                            int lane, float gk[KS]) {
    float my = 0.f;
    if (lane < KS) {
        const float* wr = w + (size_t)c * KS * KS + (size_t)lane * KS;
        #pragma unroll
        for (int j = 0; j < KS; ++j) my += wr[j];
    }
    #pragma unroll
    for (int j = 0; j < KS; ++j)
        gk[j] = __uint_as_float(__builtin_amdgcn_readlane(__float_as_uint(my), j));
}

// ---------------- Pass 1: horizontal blur, x -> ws ----------------
// One wave per row, per-wave linear LDS row buffer (halo materialized).
// Lane l computes 4 cols per segment (2 segments): the 11 ds_read_b128 window
// reads have 16B lane stride = the minimum-phase conflict-free b128 pattern
// (lanes 0..7 cover banks 0..31 exactly once). Streaming scatter into acc[4],
// all tap indices compile-time -> no win[] array, no spill.
__global__ __launch_bounds__(256, 6)
void gauss_h_kernel(const float* __restrict__ x, const float* __restrict__ w,
                    float* __restrict__ ws) {
    __shared__ float rb[4][PROW];   // 8832 B

    const int tid = threadIdx.x;
    const int wv  = tid >> 6;
    const int l   = tid & 63;
    const int img = blockIdx.y;              // 0..95
    const int c   = img % CH;
    const int row = blockIdx.x * 4 + wv;     // 0..511

    // issue row loads first so HBM latency hides under the coeff preamble
    const float* rp = x + ((size_t)img * H + row) * W;
    const float4 v0 = ((const float4*)rp)[l];
    const float4 v1 = ((const float4*)rp)[l + 64];

    float gk[KS];
    load_coeffs(w, c, l, gk);

    float* L = rb[wv];
    *(float4*)(L + PAD + 4 * l)        = v0;   // 16B lane stride: conflict-free
    *(float4*)(L + PAD + 4 * (l + 64)) = v1;
    __builtin_amdgcn_wave_barrier();

    // reflect halo: padded p<20 <- p'=40-p ; p=532..551 <- p'=1062-p
    if (l < 2 * PAD) {
        const int dstp = (l < PAD) ? l        : (512 + l);   // 0..19 | 532..551
        const int srcp = (l < PAD) ? (40 - l) : (550 - l);   // 40..21 | 530..511
        L[dstp] = L[srcp];
    }
    __builtin_amdgcn_wave_barrier();

    float* op = ws + ((size_t)img * H + row) * W;

    #pragma unroll
    for (int hh = 0; hh < 2; ++hh) {
        const int c0 = 256 * hh + 4 * l;         // output col base (mult of 4)
        const float* Lw = L + c0;                // padded window start == c0
        float a0 = 0.f, a1 = 0.f, a2 = 0.f, a3 = 0.f;

        #pragma unroll
        for (int m = 0; m < 11; ++m) {           // 44-float window, 11 quads
            const float4 q = *(const float4*)(Lw + 4 * m);
            const float f[4] = {q.x, q.y, q.z, q.w};
            #pragma unroll
            for (int t = 0; t < 4; ++t) {
                const int k = 4 * m + t;         // window pos 0..43
                if (k <= 40)            a0 += gk[k]     * f[t];
                if (k >= 1 && k <= 41)  a1 += gk[k - 1] * f[t];
                if (k >= 2 && k <= 42)  a2 += gk[k - 2] * f[t];
                if (k >= 3)             a3 += gk[k - 3] * f[t];
            }
        }
        *(float4*)(op + c0) = make_float4(a0, a1, a2, a3);  // 1KB/wave contiguous
    }
}

// ---------------- Pass 2: vertical blur, ws -> out ----------------
// (round-0 kernel, verbatim — known ~65 us) Block = 128 rows x 64 cols of
// output. Stage 168x64 ws tile (reflect rows) into LDS once, then
// sliding-column vertical conv (4B lane stride reads: conflict-free).
#define VTW 64
#define VTH 128
#define VTMPH (VTH + 2 * PAD)   // 168

__global__ __launch_bounds__(256, 3)
void gauss_v_kernel(const float* __restrict__ ws, const float* __restrict__ w,
                    float* __restrict__ out) {
    __shared__ float tmp[VTMPH * VTW];   // 43008 B

    const int tid = threadIdx.x;
    const int bx  = blockIdx.x;          // 0..7  x strip
    const int by  = blockIdx.y;          // 0..3  y tile
    const int img = blockIdx.z;          // 0..95
    const int c   = img % CH;

    float gk[KS];
    load_coeffs(w, c, tid & 63, gk);

    // stage: 168 rows x 16 quads
    const float* sbase = ws + (size_t)img * H * W + bx * VTW;
    for (int idx = tid; idx < VTMPH * 16; idx += 256) {
        const int r  = idx >> 4;
        const int q  = idx & 15;
        const int sr = reflect511(by * VTH - PAD + r);
        float4 v = *(const float4*)(sbase + (size_t)sr * W + 4 * q);
        *(float4*)&tmp[r * VTW + 4 * q] = v;
    }
    __syncthreads();

    const int lx = tid & 63;
    const int yg = tid >> 6;   // 0..3
    float* o = out + ((size_t)img * H + by * VTH) * W + bx * VTW + lx;

    #pragma unroll
    for (int cc = 0; cc < 2; ++cc) {
        const int yc = yg * 32 + cc * 16;
        float col[56];
        #pragma unroll
        for (int i = 0; i < 56; ++i)
            col[i] = tmp[(yc + i) * VTW + lx];   // 4B lane stride: conflict-free
        #pragma unroll
        for (int y = 0; y < 16; ++y) {
            float s = 0.f;
            #pragma unroll
            for (int j = 0; j < KS; ++j) s += gk[j] * col[y + j];
            o[(size_t)(yc + y) * W] = s;
        }
    }
}

// ---------------- Fallback: known-correct fused kernel ----------------
#define TW 64
#define TH 128
#define TMPH (TH + 2 * PAD)  // 168

__global__ __launch_bounds__(256, 3)
void gauss_blur_fused_kernel(const float* __restrict__ x,
                             const float* __restrict__ w,
                             float* __restrict__ out) {
    __shared__ float g_s[KS];
    __shared__ float tmp[TMPH * TW];

    const int tid = threadIdx.x;
    const int bx = blockIdx.x, by = blockIdx.y, bz = blockIdx.z;
    const int c = bz % CH;

    if (tid < KS) {
        const float* wr = w + (size_t)c * KS * KS + (size_t)tid * KS;
        float s = 0.f;
        #pragma unroll
        for (int j = 0; j < KS; ++j) s += wr[j];
        g_s[tid] = s;
    }
    __syncthreads();

    float gr[KS];
    #pragma unroll
    for (int j = 0; j < KS; ++j) gr[j] = uniform_f(g_s[j]);

    const size_t img_off = (size_t)bz * (H * W);
    const float* img = x + img_off;
    const int x_tile = bx * TW;

    for (int gid = tid; gid < TMPH * (TW / 8); gid += 256) {
        const int r  = gid >> 3;
        const int gx = gid & 7;
        const int gy = reflect_idx(by * TH - PAD + r, H);
        const int x0 = x_tile + gx * 8;
        const float* row = img + (size_t)gy * W;

        float s[8];
        #pragma unroll
        for (int k = 0; k < 8; ++k) s[k] = 0.f;

        if (x0 >= PAD && x0 + 27 <= W - 1) {
            const float4* p = (const float4*)(row + x0 - PAD);
            #pragma unroll
            for (int m = 0; m < 12; ++m) {
                const float4 v = p[m];
                const float f[4] = {v.x, v.y, v.z, v.w};
                #pragma unroll
                for (int t = 0; t < 4; ++t) {
                    const int pos = 4 * m + t;
                    #pragma unroll
                    for (int k = 0; k < 8; ++k) {
                        const int tap = pos - k;
                        if (tap >= 0 && tap < KS) s[k] += gr[tap] * f[t];
                    }
                }
            }
        } else {
            #pragma unroll
            for (int pos = 0; pos < 48; ++pos) {
                const float f = row[reflect_idx(x0 - PAD + pos, W)];
                #pragma unroll
                for (int k = 0; k < 8; ++k) {
                    const int tap = pos - k;
                    if (tap >= 0 && tap < KS) s[k] += gr[tap] * f;
                }
            }
        }
        float* dstp = &tmp[r * TW + gx * 8];
        #pragma unroll
        for (int k = 0; k < 8; ++k) dstp[k] = s[k];
    }
    __syncthreads();

    const int lx = tid & 63;
    const int yg = tid >> 6;
    float* o = out + img_off;

    #pragma unroll
    for (int cc = 0; cc < 2; ++cc) {
        const int yc = yg * 32 + cc * 16;
        float col[56];
        #pragma unroll
        for (int i = 0; i < 56; ++i)
            col[i] = tmp[(yc + i) * TW + lx];
        #pragma unroll
        for (int y = 0; y < 16; ++y) {
            float s = 0.f;
            #pragma unroll
            for (int j = 0; j < KS; ++j) s += gr[j] * col[y + j];
            o[(size_t)(by * TH + yc + y) * W + x_tile + lx] = s;
        }
    }
}

extern "C" void kernel_launch(void* const* d_in, const int* in_sizes, int n_in,
                              void* d_out, int out_size, void* d_ws, size_t ws_size,
                              hipStream_t stream) {
    const float* x = (const float*)d_in[0];   // [16,6,512,512]
    const float* w = (const float*)d_in[1];   // [6,1,41,41]
    float* out = (float*)d_out;
    (void)in_sizes; (void)n_in; (void)out_size;

    const size_t need = (size_t)16 * CH * H * W * sizeof(float);
    if (ws_size >= need) {
        float* ws = (float*)d_ws;
        gauss_h_kernel<<<dim3(H / 4, 16 * CH), 256, 0, stream>>>(x, w, ws);
        gauss_v_kernel<<<dim3(W / VTW, H / VTH, 16 * CH), 256, 0, stream>>>(ws, w, out);
    } else {
        dim3 grid(W / TW, H / TH, 16 * CH);
        gauss_blur_fused_kernel<<<grid, 256, 0, stream>>>(x, w, out);
    }
}

// Round 5
// 245.514 us; speedup vs baseline: 3.3037x; 1.0305x over previous
//
#include <hip/hip_runtime.h>

#define KS 41
#define PAD 20
#define H 512
#define W 512
#define CH 6

// Transposed-output horizontal blur tile geometry
#define TR 64                  // tile rows (input rows, lane = row)
#define TC 128                 // tile cols (output cols)
#define PC (TC + 2 * PAD)      // 168 padded cols
#define LSTR 65                // LDS row stride; 65 % 32 == 1 -> conflict-free both ways
#define WCOL 32                // cols per wave (4 waves)
#define CWIN (WCOL + 2 * PAD)  // 72-float sliding register window

__device__ __forceinline__ int reflect_idx(int i, int n) {
    if (i < 0) i = -i;
    if (i >= n) i = 2 * n - 2 - i;
    return i;
}

__device__ __forceinline__ int reflect511(int i) {
    // valid for i in (-512, 1022); H == W == 512
    return (H - 1) - abs((H - 1) - abs(i));
}

__device__ __forceinline__ float uniform_f(float v) {
    return __uint_as_float(__builtin_amdgcn_readfirstlane(__float_as_uint(v)));
}

// Coefficients -> SGPRs, no LDS, no barrier: lane j (j<41) computes row-sum j
// of the separable 2D kernel (== normalized 1D gaussian), readlane broadcasts.
__device__ __forceinline__ void load_coeffs(const float* __restrict__ w, int c,
                                            int lane, float gk[KS]) {
    float my = 0.f;
    if (lane < KS) {
        const float* wr = w + (size_t)c * KS * KS + (size_t)lane * KS;
        #pragma unroll
        for (int j = 0; j < KS; ++j) my += wr[j];
    }
    #pragma unroll
    for (int j = 0; j < KS; ++j)
        gk[j] = __uint_as_float(__builtin_amdgcn_readlane(__float_as_uint(my), j));
}

// Horizontal blur with TRANSPOSED output: outT[c][r] = sum_j g[j]*in[r][refl(c-20+j)].
// Applied twice == full separable blur, final orientation restored.
// All LDS traffic is b32 at 4B lane stride (2 lanes/bank = free, m136):
//   staging writes tmp[p*65+r]: consecutive lanes -> p+1 -> bank+1
//   compute reads  tmp[i*65+l]: consecutive lanes -> r+1 -> bank+1
// Global: reads 4B-stride coalesced; stores 256B contiguous per instruction.
__global__ __launch_bounds__(256, 3)
void hblurT_kernel(const float* __restrict__ in, const float* __restrict__ w,
                   float* __restrict__ outT) {
    __shared__ float tmp[PC * LSTR];   // 43680 B -> 3 blocks/CU

    const int tid = threadIdx.x;
    const int wv  = tid >> 6;
    const int l   = tid & 63;
    const int img = blockIdx.z;            // 0..95
    const int c   = img % CH;
    const int c0  = blockIdx.x * TC;       // 0..384
    const int r0  = blockIdx.y * TR;       // 0..448

    float gk[KS];
    load_coeffs(w, c, l, gk);

    // stage 64 rows x 168 padded cols, transposed into LDS
    const float* ip = in + (size_t)img * H * W;
    #pragma unroll
    for (int k = 0; k < (TR * PC) / 256; ++k) {   // 42 iterations, exact
        const int t = k * 256 + tid;
        const int r = t / PC;
        const int p = t - r * PC;
        tmp[p * LSTR + r] = ip[(size_t)(r0 + r) * W + reflect511(c0 - PAD + p)];
    }
    __syncthreads();

    // wave wv -> output cols c0 + 32*wv .. +31 ; lane l -> row r0 + l
    float col[CWIN];
    #pragma unroll
    for (int i = 0; i < CWIN; ++i)
        col[i] = tmp[(WCOL * wv + i) * LSTR + l];

    float* op = outT + (size_t)img * H * W + (size_t)(c0 + WCOL * wv) * H + r0 + l;
    #pragma unroll
    for (int u = 0; u < WCOL; ++u) {
        float s = 0.f;
        #pragma unroll
        for (int j = 0; j < KS; ++j) s += gk[j] * col[u + j];
        op[(size_t)u * H] = s;   // lanes contiguous: 256B/instruction
    }
}

// ---------------- Fallback: known-correct fused kernel ----------------
#define TW 64
#define TH 128
#define TMPH (TH + 2 * PAD)  // 168

__global__ __launch_bounds__(256, 3)
void gauss_blur_fused_kernel(const float* __restrict__ x,
                             const float* __restrict__ w,
                             float* __restrict__ out) {
    __shared__ float g_s[KS];
    __shared__ float tmp[TMPH * TW];

    const int tid = threadIdx.x;
    const int bx = blockIdx.x, by = blockIdx.y, bz = blockIdx.z;
    const int c = bz % CH;

    if (tid < KS) {
        const float* wr = w + (size_t)c * KS * KS + (size_t)tid * KS;
        float s = 0.f;
        #pragma unroll
        for (int j = 0; j < KS; ++j) s += wr[j];
        g_s[tid] = s;
    }
    __syncthreads();

    float gr[KS];
    #pragma unroll
    for (int j = 0; j < KS; ++j) gr[j] = uniform_f(g_s[j]);

    const size_t img_off = (size_t)bz * (H * W);
    const float* img = x + img_off;
    const int x_tile = bx * TW;

    for (int gid = tid; gid < TMPH * (TW / 8); gid += 256) {
        const int r  = gid >> 3;
        const int gx = gid & 7;
        const int gy = reflect_idx(by * TH - PAD + r, H);
        const int x0 = x_tile + gx * 8;
        const float* row = img + (size_t)gy * W;

        float s[8];
        #pragma unroll
        for (int k = 0; k < 8; ++k) s[k] = 0.f;

        if (x0 >= PAD && x0 + 27 <= W - 1) {
            const float4* p = (const float4*)(row + x0 - PAD);
            #pragma unroll
            for (int m = 0; m < 12; ++m) {
                const float4 v = p[m];
                const float f[4] = {v.x, v.y, v.z, v.w};
                #pragma unroll
                for (int t = 0; t < 4; ++t) {
                    const int pos = 4 * m + t;
                    #pragma unroll
                    for (int k = 0; k < 8; ++k) {
                        const int tap = pos - k;
                        if (tap >= 0 && tap < KS) s[k] += gr[tap] * f[t];
                    }
                }
            }
        } else {
            #pragma unroll
            for (int pos = 0; pos < 48; ++pos) {
                const float f = row[reflect_idx(x0 - PAD + pos, W)];
                #pragma unroll
                for (int k = 0; k < 8; ++k) {
                    const int tap = pos - k;
                    if (tap >= 0 && tap < KS) s[k] += gr[tap] * f;
                }
            }
        }
        float* dstp = &tmp[r * TW + gx * 8];
        #pragma unroll
        for (int k = 0; k < 8; ++k) dstp[k] = s[k];
    }
    __syncthreads();

    const int lx = tid & 63;
    const int yg = tid >> 6;
    float* o = out + img_off;

    #pragma unroll
    for (int cc = 0; cc < 2; ++cc) {
        const int yc = yg * 32 + cc * 16;
        float col[56];
        #pragma unroll
        for (int i = 0; i < 56; ++i)
            col[i] = tmp[(yc + i) * TW + lx];
        #pragma unroll
        for (int y = 0; y < 16; ++y) {
            float s = 0.f;
            #pragma unroll
            for (int j = 0; j < KS; ++j) s += gr[j] * col[y + j];
            o[(size_t)(by * TH + yc + y) * W + x_tile + lx] = s;
        }
    }
}

extern "C" void kernel_launch(void* const* d_in, const int* in_sizes, int n_in,
                              void* d_out, int out_size, void* d_ws, size_t ws_size,
                              hipStream_t stream) {
    const float* x = (const float*)d_in[0];   // [16,6,512,512]
    const float* w = (const float*)d_in[1];   // [6,1,41,41]
    float* out = (float*)d_out;
    (void)in_sizes; (void)n_in; (void)out_size;

    const size_t need = (size_t)16 * CH * H * W * sizeof(float);
    if (ws_size >= need) {
        float* ws = (float*)d_ws;
        const dim3 grid(W / TC, H / TR, 16 * CH);   // (4, 8, 96)
        hblurT_kernel<<<grid, 256, 0, stream>>>(x,  w, ws);   // x -> hblur^T
        hblurT_kernel<<<grid, 256, 0, stream>>>(ws, w, out);  // -> full blur, normal orientation
    } else {
        dim3 grid(W / TW, H / TH, 16 * CH);
        gauss_blur_fused_kernel<<<grid, 256, 0, stream>>>(x, w, out);
    }
}